// Round 5
// baseline (958.946 us; speedup 1.0000x reference)
//
#include <hip/hip_runtime.h>
#include <math.h>

// SSIM loss, fused single-pass. fp32 [32,1,1024,1024] x2 -> scalar.
// Separable 11x11 Gaussian of 5 fields {a,b,a2,b2,ab}.
// Round-10: batched phases. r9 (2-phase load slack) REGRESSED 174->193
// (+16 VGPR, occupancy -5) => floor is NOT per-load residual latency.
// Empirical law from r7->r8: dur = ~119us structural floor + VALU-issue
// wall; floor = 74 phases x ~3800cyc of per-phase overhead (barrier
// vmcnt/lgkmcnt drain, LDS-latency exposure at phase start, lockstep).
// Fix: re-batch to CH=4 rows per barrier phase, double-buffered 4-row LDS
// chunks -> 19 barriers instead of 74, 4x ILP window (44 ds_reads + ~350
// VALU per barrier-free region), 4x fewer vmcnt drains. Arithmetic, ring
// indexing (u = s%11 compile-time via 11-batch super-iteration), packed
// VOP3P math, pre-paired SGPR weights all identical to r8. Staging 16 regs,
// LDS 17.2KB.
// Tile 256 cols x 64 rows; grid 4x16x32 = 2048 blocks = 8/CU.

typedef float v2f __attribute__((ext_vector_type(2)));

#define IMG_W 1024
#define IMG_H 1024
#define NIMG  32
#define TW    256
#define TH    64
#define HALO  5
#define KW    11
#define ROWS  (TH + 2*HALO)   // 74 staged rows
#define CH    4               // rows per barrier phase
#define NBAT  19              // ceil(74/4) batches
#define SBP   268             // LDS row stride in v2f (266 used, 16B-pad)

#define C1f (0.01f * 0.01f)
#define C2f (0.03f * 0.03f)

struct GW { v2f wp[KW]; };    // wp[i] = (w[i], w[i]) -- pre-paired for VOP3P

__global__ __launch_bounds__(256, 2)
void ssim_main(const float* __restrict__ img1, const float* __restrict__ img2,
               double* __restrict__ acc_out, GW gw)
{
    alignas(16) __shared__ v2f sb[2][CH * SBP];
    __shared__ float wsum[4];

    const int tid = threadIdx.x;
    const int c0 = blockIdx.x * TW;
    const int r0 = blockIdx.y * TH;
    const size_t imgoff = (size_t)blockIdx.z * (size_t)(IMG_W * IMG_H);
    const float* p1 = img1 + imgoff;
    const float* p2 = img2 + imgoff;

    // column geometry (uniform over rows); addresses clamped, OOB zeroed by select
    const int  gc_m   = c0 - HALO + tid;
    const int  gcc_m  = min(max(gc_m, 0), IMG_W - 1);
    const bool cok_m  = ((unsigned)gc_m < (unsigned)IMG_W);
    const int  gc_h   = c0 - HALO + TW + tid;            // used by tid<10
    const int  gcc_h  = min(max(gc_h, 0), IMG_W - 1);
    const bool cok_h  = (tid < 2 * HALO) && ((unsigned)gc_h < (unsigned)IMG_W);

    // vertical ring: (m1,m2) pairs, (sa,sb) pairs, ab scalar = 55 floats
    v2f  r_m[KW], r_s[KW];
    float r_ab[KW];
#pragma unroll
    for (int j = 0; j < KW; ++j) {
        r_m[j] = (v2f)0.f; r_s[j] = (v2f)0.f; r_ab[j] = 0.f;
    }

    float lsum = 0.0f;

    // one staging set for a 4-row batch: [a_main, b_main, a_halo, b_halo] x CH
    float st0[CH], st1[CH], st2[CH], st3[CH];

    auto issue = [&](int b) {           // global -> staging regs for batch b
#pragma unroll
        for (int q = 0; q < CH; ++q) {
            const int s = b * CH + q;
            const int gr  = r0 + s - HALO;
            const bool rok = ((unsigned)gr < (unsigned)IMG_H);
            const size_t rbase = (size_t)min(max(gr, 0), IMG_H - 1) * IMG_W;
            float a0 = p1[rbase + gcc_m];
            float b0 = p2[rbase + gcc_m];
            float a1 = p1[rbase + gcc_h];
            float b1 = p2[rbase + gcc_h];
            const bool okm = rok && cok_m;
            const bool okh = rok && cok_h;
            st0[q] = okm ? a0 : 0.f;
            st1[q] = okm ? b0 : 0.f;
            st2[q] = okh ? a1 : 0.f;
            st3[q] = okh ? b1 : 0.f;
        }
    };
    auto commit = [&](int b) {          // staging regs -> LDS buffer b&1
        v2f* dst = sb[b & 1];
#pragma unroll
        for (int q = 0; q < CH; ++q) {
            v2f t; t.x = st0[q]; t.y = st1[q];
            dst[q * SBP + tid] = t;
            if (tid < 2 * HALO) {
                v2f t2; t2.x = st2[q]; t2.y = st3[q];
                dst[q * SBP + TW + tid] = t2;
            }
        }
    };

    // prologue: batch 0 straight to LDS; batch 1 in flight in regs
    issue(0); commit(0);
    issue(1);

    // phases p = 0..18; batch p computed from buf p&1 (committed at phase p-1)
    for (int sup = 0; sup < 2; ++sup) {
#pragma unroll
        for (int bq = 0; bq < KW; ++bq) {
            const int p = sup * KW + bq;
            if (p < NBAT) {                       // compile-time dead for p>=19
                __syncthreads();                  // phase p-1 reads done everywhere
                if (p + 1 < NBAT) commit(p + 1);  // staged loads from phase p-1
                if (p + 2 < NBAT) issue(p + 2);   // refill staging, 1 phase slack

                const v2f* buf = sb[p & 1];
#pragma unroll
                for (int q = 0; q < CH; ++q) {
                    const int s = p * CH + q;
                    if (s < ROWS) {               // tail rows 74,75 dead
                        const int u = (bq * CH + q) % KW;   // == s % 11

                        // horizontal 11-tap conv, packed
                        const v2f* b = buf + q * SBP;
                        v2f hm = (v2f)0.f, hs = (v2f)0.f;
                        float hab = 0.f;
#pragma unroll
                        for (int i = 0; i < KW; ++i) {
                            const v2f E  = b[tid + i];    // (a, b) packed
                            const v2f wv = gw.wp[i];      // (w, w) SGPR pair
                            hm = __builtin_elementwise_fma(wv, E, hm);   // pk_fma
                            const v2f P = E * E;                         // pk_mul
                            hs = __builtin_elementwise_fma(wv, P, hs);   // pk_fma
                            hab = __builtin_fmaf(wv.x, E.x * E.y, hab);  // mul+fma
                        }

                        // vertical ring accumulate; slot j fresh-starts when k==0
#pragma unroll
                        for (int j = 0; j < KW; ++j) {
                            const int k = (u - j + KW) % KW;  // compile-time
                            const v2f  wv = gw.wp[k];
                            const float wk = wv.x;
                            if (k == 0) {
                                r_m[j] = wv * hm;
                                r_s[j] = wv * hs;
                                r_ab[j] = wk * hab;
                            } else {
                                r_m[j] = __builtin_elementwise_fma(wv, hm, r_m[j]);
                                r_s[j] = __builtin_elementwise_fma(wv, hs, r_s[j]);
                                r_ab[j] = __builtin_fmaf(wk, hab, r_ab[j]);
                            }
                        }

                        // output row r = s-10 completes in slot (u+1)%11
                        if (s >= 10) {
                            const int je = (u + 1) % KW;
                            const v2f  mu  = r_m[je];          // (mu1, mu2)
                            const v2f  cs  = r_s[je];          // (caa, cbb)
                            const float cab = r_ab[je];
                            const v2f  mus = mu * mu;
                            const float mu12 = mu.x * mu.y;
                            const v2f  sg  = cs - mus;
                            const float sg12 = cab - mu12;
                            const float num = (2.0f * mu12 + C1f) * (2.0f * sg12 + C2f);
                            const float den = (mus.x + mus.y + C1f) * (sg.x + sg.y + C2f);
                            lsum = __builtin_fmaf(num, __builtin_amdgcn_rcpf(den), lsum);
                        }
                    }
                }
            }
        }
    }

    // block reduction: wave shuffle then LDS across the 4 waves
    float v = lsum;
#pragma unroll
    for (int off = 32; off > 0; off >>= 1) v += __shfl_down(v, off);
    __syncthreads();
    if ((tid & 63) == 0) wsum[tid >> 6] = v;
    __syncthreads();
    if (tid == 0) {
        float bsum = wsum[0] + wsum[1] + wsum[2] + wsum[3];
        atomicAdd(acc_out, (double)bsum);
    }
}

__global__ void ssim_finalize(const double* __restrict__ acc, float* __restrict__ out)
{
    out[0] = 1.0f - (float)(acc[0] * (1.0 / ((double)NIMG * IMG_W * IMG_H)));
}

extern "C" void kernel_launch(void* const* d_in, const int* in_sizes, int n_in,
                              void* d_out, int out_size, void* d_ws, size_t ws_size,
                              hipStream_t stream)
{
    const float* img1 = (const float*)d_in[0];
    const float* img2 = (const float*)d_in[1];
    float* out = (float*)d_out;
    double* accbuf = (double*)d_ws;

    // Gaussian weights exactly as the reference: exp in f64, cast f32, normalize
    GW gw;
    {
        float g[KW];
        double s = 0.0;
        for (int i = 0; i < KW; ++i) {
            int x = i - KW / 2;
            g[i] = (float)exp(-(double)(x * x) / (2.0 * 1.5 * 1.5));
            s += (double)g[i];
        }
        for (int i = 0; i < KW; ++i) {
            float w = (float)((double)g[i] / s);
            gw.wp[i].x = w;
            gw.wp[i].y = w;
        }
    }

    hipMemsetAsync(accbuf, 0, sizeof(double), stream);
    dim3 grid(IMG_W / TW, IMG_H / TH, NIMG);
    ssim_main<<<grid, 256, 0, stream>>>(img1, img2, accbuf, gw);
    ssim_finalize<<<1, 1, 0, stream>>>(accbuf, out);
}

// Round 6
// 332.959 us; speedup vs baseline: 2.8801x; 2.8801x over previous
//
#include <hip/hip_runtime.h>
#include <math.h>

// SSIM loss, fused single-pass. fp32 [32,1,1024,1024] x2 -> scalar.
// Separable 11x11 Gaussian of 5 fields {a,b,a2,b2,ab}.
// Round-11: BARRIER-FREE wave-private streaming. r10 (CH=4 reg batching)
// spilled to scratch (WRITE_SIZE 64KB->1.29GB, VALUBusy 14%) -> allocator
// caps at 128 VGPR and spills rather than exceed occupancy target; register
// batching is dead. r9/r10 both attacked the 74-barrier lockstep but were
// confounded by VGPR side-effects. This round removes the barriers
// themselves: each of the 4 waves owns a 64-output-col strip and stages its
// own 74-col rows (64 main + 10 halo) into a wave-PRIVATE LDS double buffer.
// No __syncthreads in the main loop; in-wave ds ordering enforced by
// compiler lgkmcnt (ordered, partial waits). Waves drift freely -> a stalled
// wave no longer gates the other 3 at a barrier. Arithmetic, packed VOP3P
// math, SGPR weights, staging depth (issue 2 ahead, commit 1 ahead) all
// r8-identical; VGPR stays ~50. Cost: per-wave horizontal halo -> FETCH +11%.
// Tile 256 cols (4x64 per wave) x 64 rows; grid 4x16x32 = 2048 blocks.

typedef float v2f __attribute__((ext_vector_type(2)));

#define IMG_W 1024
#define IMG_H 1024
#define NIMG  32
#define TW    256             // block tile width (4 waves x 64)
#define TH    64
#define HALO  5
#define KW    11
#define ROWS  (TH + 2*HALO)   // 74 staged rows
#define NSO   7               // 7*11 = 77 unrolled steps, tail guarded off
#define SBW   76              // wave strip stride in v2f (74 used, 16B-pad)

#define C1f (0.01f * 0.01f)
#define C2f (0.03f * 0.03f)

struct GW { v2f wp[KW]; };    // wp[i] = (w[i], w[i]) -- pre-paired for VOP3P

__global__ __launch_bounds__(256, 2)
void ssim_main(const float* __restrict__ img1, const float* __restrict__ img2,
               double* __restrict__ acc_out, GW gw)
{
    alignas(16) __shared__ v2f sb[4][2][SBW];   // [wave][dbuf][strip]
    __shared__ float wsum[4];

    const int tid = threadIdx.x;
    const int wv  = tid >> 6;          // wave id 0..3
    const int l   = tid & 63;          // lane
    const int c0 = blockIdx.x * TW + wv * 64;   // wave's output col base
    const int r0 = blockIdx.y * TH;
    const size_t imgoff = (size_t)blockIdx.z * (size_t)(IMG_W * IMG_H);
    const float* p1 = img1 + imgoff;
    const float* p2 = img2 + imgoff;

    // column geometry (uniform over rows); addresses clamped, OOB zeroed by select
    const int  gc_m   = c0 - HALO + l;                   // strip idx l
    const int  gcc_m  = min(max(gc_m, 0), IMG_W - 1);
    const bool cok_m  = ((unsigned)gc_m < (unsigned)IMG_W);
    const int  gc_h   = c0 - HALO + 64 + l;              // strip idx 64+l, used l<10
    const int  gcc_h  = min(max(gc_h, 0), IMG_W - 1);
    const bool cok_h  = (l < 2 * HALO) && ((unsigned)gc_h < (unsigned)IMG_W);

    // vertical ring: (m1,m2) pairs, (sa,sb) pairs, ab scalar = 55 floats
    v2f  r_m[KW], r_s[KW];
    float r_ab[KW];
#pragma unroll
    for (int j = 0; j < KW; ++j) {
        r_m[j] = (v2f)0.f; r_s[j] = (v2f)0.f; r_ab[j] = 0.f;
    }

    float lsum = 0.0f;

    // staging registers for one row: [a_main, b_main, a_halo, b_halo]
    float s0, s1, s2, s3;

    auto issue = [&](int s) {           // global -> regs for staged row s
        const int gr  = r0 + s - HALO;
        const bool rok = ((unsigned)gr < (unsigned)IMG_H);
        const size_t rbase = (size_t)min(max(gr, 0), IMG_H - 1) * IMG_W;
        float a0 = p1[rbase + gcc_m];
        float b0 = p2[rbase + gcc_m];
        float a1 = p1[rbase + gcc_h];
        float b1 = p2[rbase + gcc_h];
        const bool okm = rok && cok_m;
        const bool okh = rok && cok_h;
        s0 = okm ? a0 : 0.f;
        s1 = okm ? b0 : 0.f;
        s2 = okh ? a1 : 0.f;
        s3 = okh ? b1 : 0.f;
    };
    auto commit = [&](int s) {          // regs -> wave-private LDS buffer s&1
        v2f* dst = sb[wv][s & 1];
        v2f t; t.x = s0; t.y = s1;
        dst[l] = t;
        if (l < 2 * HALO) { v2f t2; t2.x = s2; t2.y = s3; dst[64 + l] = t2; }
    };

    issue(0); commit(0);    // row 0 straight to LDS
    issue(1);               // row 1 in flight in regs

    for (int so = 0; so < NSO; ++so) {
#pragma unroll
        for (int u = 0; u < KW; ++u) {
            const int s = so * KW + u;
            if (s < ROWS) {                 // uniform guard (tail steps dead)
                // NO barrier: wave-private buffers; lgkmcnt orders ds ops in-wave
                if (s + 1 < ROWS) commit(s + 1);
                if (s + 2 < ROWS) issue(s + 2);

                // horizontal 11-tap conv, packed: hm=(m1,m2) hs=(sa,sb) hab scalar
                const v2f* b = sb[wv][s & 1];
                v2f hm = (v2f)0.f, hs = (v2f)0.f;
                float hab = 0.f;
#pragma unroll
                for (int i = 0; i < KW; ++i) {
                    const v2f E  = b[l + i];          // (a, b) packed
                    const v2f wv2 = gw.wp[i];         // (w, w) SGPR pair
                    hm = __builtin_elementwise_fma(wv2, E, hm);       // pk_fma
                    const v2f P = E * E;                              // pk_mul
                    hs = __builtin_elementwise_fma(wv2, P, hs);       // pk_fma
                    hab = __builtin_fmaf(wv2.x, E.x * E.y, hab);      // mul+fma
                }

                // vertical ring accumulate; slot j fresh-starts when k==0
#pragma unroll
                for (int j = 0; j < KW; ++j) {
                    const int k = (u - j + KW) % KW;   // compile-time after unroll
                    const v2f  wk2 = gw.wp[k];
                    const float wk = wk2.x;
                    if (k == 0) {
                        r_m[j] = wk2 * hm;                             // pk_mul
                        r_s[j] = wk2 * hs;                             // pk_mul
                        r_ab[j] = wk * hab;
                    } else {
                        r_m[j] = __builtin_elementwise_fma(wk2, hm, r_m[j]);
                        r_s[j] = __builtin_elementwise_fma(wk2, hs, r_s[j]);
                        r_ab[j] = __builtin_fmaf(wk, hab, r_ab[j]);
                    }
                }

                // output row r = s-10 completes in slot (u+1)%11
                if (s >= 10) {
                    const int je = (u + 1) % KW;
                    const v2f  mu  = r_m[je];          // (mu1, mu2)
                    const v2f  cs  = r_s[je];          // (caa, cbb)
                    const float cab = r_ab[je];
                    const v2f  mus = mu * mu;          // (mu1^2, mu2^2)
                    const float mu12 = mu.x * mu.y;
                    const v2f  sg  = cs - mus;         // (sg1, sg2)
                    const float sg12 = cab - mu12;
                    const float num = (2.0f * mu12 + C1f) * (2.0f * sg12 + C2f);
                    const float den = (mus.x + mus.y + C1f) * (sg.x + sg.y + C2f);
                    lsum = __builtin_fmaf(num, __builtin_amdgcn_rcpf(den), lsum);
                }
            }
        }
    }

    // block reduction: wave shuffle then LDS across the 4 waves
    float v = lsum;
#pragma unroll
    for (int off = 32; off > 0; off >>= 1) v += __shfl_down(v, off);
    __syncthreads();
    if ((tid & 63) == 0) wsum[tid >> 6] = v;
    __syncthreads();
    if (tid == 0) {
        float bsum = wsum[0] + wsum[1] + wsum[2] + wsum[3];
        atomicAdd(acc_out, (double)bsum);
    }
}

__global__ void ssim_finalize(const double* __restrict__ acc, float* __restrict__ out)
{
    out[0] = 1.0f - (float)(acc[0] * (1.0 / ((double)NIMG * IMG_W * IMG_H)));
}

extern "C" void kernel_launch(void* const* d_in, const int* in_sizes, int n_in,
                              void* d_out, int out_size, void* d_ws, size_t ws_size,
                              hipStream_t stream)
{
    const float* img1 = (const float*)d_in[0];
    const float* img2 = (const float*)d_in[1];
    float* out = (float*)d_out;
    double* accbuf = (double*)d_ws;

    // Gaussian weights exactly as the reference: exp in f64, cast f32, normalize
    GW gw;
    {
        float g[KW];
        double s = 0.0;
        for (int i = 0; i < KW; ++i) {
            int x = i - KW / 2;
            g[i] = (float)exp(-(double)(x * x) / (2.0 * 1.5 * 1.5));
            s += (double)g[i];
        }
        for (int i = 0; i < KW; ++i) {
            float w = (float)((double)g[i] / s);
            gw.wp[i].x = w;
            gw.wp[i].y = w;
        }
    }

    hipMemsetAsync(accbuf, 0, sizeof(double), stream);
    dim3 grid(IMG_W / TW, IMG_H / TH, NIMG);
    ssim_main<<<grid, 256, 0, stream>>>(img1, img2, accbuf, gw);
    ssim_finalize<<<1, 1, 0, stream>>>(accbuf, out);
}